// Round 3
// baseline (393.414 us; speedup 1.0000x reference)
//
#include <hip/hip_runtime.h>
#include <math.h>

// LIF first-spike time, closed form:
//   a = 0.8 ; n = max(ceil(log(1 - 1/I)/log(a)), 1) ; t = 0.01*n ; I<=1 -> sentinel
//
// v5b: same as v5 but using a clang native vector type (ext_vector_type) for the
// nontemporal builtins — HIP's float4 is a class type, which
// __builtin_nontemporal_load/store rejects (R2 compile failure).
//
// v5 changes vs v4 (verified at 396 us):
//  - removed the n<=200000 clamp: for fp32 I>1, I-1 >= 2^-23 (Sterbenz-exact
//    subtraction), so log2(I-1) >= -23 and n <= ~72 << 200000. Provably dead.
//  - 2-deep MLP unroll: two independent 16B loads in flight per thread
//    before any compute (hides the dependent v_log chain + HBM latency).
//  - int32 indexing in the hot loop (nvec = 16M << 2^31) — no 64-bit mads.
//  - nontemporal load/store: both streams are touch-once; avoid L2/L3 churn
//    (512 MB working set vs 256 MB L3).
// Math is unchanged from the harness-verified v4:
//   log(1 - 1/I)/log(a) = (log2(I-1) - log2(I)) * (1/log2(0.8))
// plus bit-level finite scrub so no NaN/inf ever reaches memory.

#define SENTINEL_F 1.0e30f
#define INV_LOG2_A (-3.1062837f) /* 1 / log2(0.8f) */

typedef float f32x4 __attribute__((ext_vector_type(4)));

__device__ __forceinline__ float spike_time_fast(float cur) {
    float la = __log2f(cur - 1.0f);  // v_log_f32; NaN/-inf only when cur <= 1
    float lb = __log2f(cur);         // v_log_f32
    float nr = (la - lb) * INV_LOG2_A;
    float nn = fmaxf(ceilf(nr), 1.0f);
    float r = (cur > 1.0f) ? nn * 0.01f : SENTINEL_F;

    // bit-level finite scrub (exp field all-ones == inf/NaN) — NaN can never
    // reach memory regardless of compiler float semantics.
    unsigned int b = __float_as_uint(r);
    if ((b & 0x7f800000u) == 0x7f800000u) {
        r = SENTINEL_F;
    }
    return r;
}

__device__ __forceinline__ f32x4 spike4(f32x4 v) {
    f32x4 r;
    r.x = spike_time_fast(v.x);
    r.y = spike_time_fast(v.y);
    r.z = spike_time_fast(v.z);
    r.w = spike_time_fast(v.w);
    return r;
}

__global__ __launch_bounds__(256) void lif_spike_v5(const f32x4* __restrict__ in4,
                                                    f32x4* __restrict__ out4,
                                                    int nvec) {
    const int gid = blockIdx.x * blockDim.x + threadIdx.x;
    const int gstride = gridDim.x * blockDim.x;

    int i = gid;
    // 2-deep unrolled grid-stride: both loads issued before either compute.
    for (; i + gstride < nvec; i += 2 * gstride) {
        f32x4 a = __builtin_nontemporal_load(in4 + i);
        f32x4 b = __builtin_nontemporal_load(in4 + i + gstride);
        f32x4 ra = spike4(a);
        f32x4 rb = spike4(b);
        __builtin_nontemporal_store(ra, out4 + i);
        __builtin_nontemporal_store(rb, out4 + i + gstride);
    }
    // tail (at most one strided element per thread)
    for (; i < nvec; i += gstride) {
        f32x4 a = __builtin_nontemporal_load(in4 + i);
        __builtin_nontemporal_store(spike4(a), out4 + i);
    }
}

__global__ __launch_bounds__(256) void lif_spike_v5_scalar(const float* __restrict__ in,
                                                           float* __restrict__ out,
                                                           int nelem) {
    const long long gid0 = (long long)blockIdx.x * blockDim.x + threadIdx.x;
    const long long gstride = (long long)gridDim.x * blockDim.x;
    for (long long i = gid0; i < nelem; i += gstride) {
        out[i] = spike_time_fast(in[i]);
    }
}

extern "C" void kernel_launch(void* const* d_in, const int* in_sizes, int n_in,
                              void* d_out, int out_size, void* d_ws, size_t ws_size,
                              hipStream_t stream) {
    const float* in = (const float*)d_in[0];
    float* out = (float*)d_out;
    const int n = in_sizes[0]; // 64 * 1,000,000 fp32

    const bool aligned16 = ((((uintptr_t)in) | ((uintptr_t)out)) & 0xF) == 0;

    if (aligned16 && (n & 3) == 0) {
        const int block = 256;
        const int nvec = n >> 2;                       // 16,000,000
        long long grid = ((long long)nvec + 2LL * block - 1) / (2LL * block); // 31,250
        if (grid < 1) grid = 1;
        if (grid > 1048576) grid = 1048576;
        lif_spike_v5<<<(int)grid, block, 0, stream>>>((const f32x4*)in, (f32x4*)out, nvec);
    } else {
        const int block = 256;
        long long grid = ((long long)n + block - 1) / block;
        if (grid < 1) grid = 1;
        if (grid > 1048576) grid = 1048576;
        lif_spike_v5_scalar<<<(int)grid, block, 0, stream>>>(in, out, n);
    }
}